// Round 16
// baseline (106.194 us; speedup 1.0000x reference)
//
#include <hip/hip_runtime.h>

// OpeningP4: x [4,4,64,64,8] f32, kernel [3,3,3,8,16] f32 -> out [4,4,64,64,16] f32.
// v16 = R14 (91.5us PASSED, swizzle reverted) + j-FUSED dilate:
//  block = (b, hs:16, ws:8); thread owns all 4 j x 4 out rows of one (w,c,q) column.
//  Per gsrc plane the 3 (j,k) consumer pairs (j=(gsrc+1-k)%4) share each ero row
//  load -> 72 loads/16 outputs vs 90/8 (2.5x less traffic, ~1x HBM fetch per elem).
// Erode verbatim from R14. Rotation algebra from PASSED rounds (absmax 0.0625).

#define HH 64
#define WW 64
#define NEG_INF (-__builtin_inff())
#define POS_INF (__builtin_inff())

#define ROT_G(G, A, B, I, J) do { switch (G) { \
    case 0:  I = (A);     J = (B);     break; \
    case 1:  I = (B);     J = 2 - (A); break; \
    case 2:  I = 2 - (A); J = 2 - (B); break; \
    default: I = 2 - (B); J = (A);     break; } } while (0)

typedef _Float16 hv4 __attribute__((ext_vector_type(4)));   // 8 B, v_pk_* pairs

__device__ __forceinline__ hv4 f4_to_hv4(float4 v) {
    hv4 r;
    r.x = (_Float16)v.x; r.y = (_Float16)v.y;
    r.z = (_Float16)v.z; r.w = (_Float16)v.w;
    return r;
}

__device__ __forceinline__ hv4 bcast16(float v) {
    _Float16 p = (_Float16)v;
    return (hv4){p, p, p, p};
}

// ======================= kernel 1: erosion (packed f16 math) ======================
// block = (b,g,h); thread = (slot,c,q); pixels w = slot*8 + i, i=0..7 (consecutive).
// ero layout (hv4 elems): ((bg*64+h)*66 + wp)*32 + c*4 + q, wp = w+1, -inf borders.
__global__ __launch_bounds__(256) void erode_t(const float* __restrict__ x,
                                               const float* __restrict__ ker,
                                               hv4* __restrict__ ero) {
    __shared__ __align__(16) float xs[9 * 8 * 68];   // 19584 B

    const int tid = threadIdx.x;
    const int h = blockIdx.x & 63;
    const int g = (blockIdx.x >> 6) & 3;
    const int b = blockIdx.x >> 8;

    const float4* x4 = (const float4*)x;
    const float4* ker4 = (const float4*)ker;

    // stage 3 planes x[(g+p-1)&3], rows h-1..h+1, cols -1..64 (wp 0..65), OOB=+inf
    for (int t = tid; t < 1188; t += 256) {
        int q01 = t & 1;
        int u = t >> 1;
        int wp = u % 66;
        int v = u / 66;
        int r = v % 3;
        int p = v / 3;
        int g2 = (g + p + 3) & 3;
        int h2 = h - 1 + r;
        int w2 = wp - 1;
        float4 vv;
        if ((unsigned)h2 < HH && (unsigned)w2 < WW)
            vv = x4[(((b * 4 + g2) * HH + h2) * WW + w2) * 2 + q01];
        else
            vv = make_float4(POS_INF, POS_INF, POS_INF, POS_INF);
        int rowb = (p * 3 + r) * 8 + q01 * 4;
        xs[(rowb + 0) * 68 + wp] = vv.x;
        xs[(rowb + 1) * 68 + wp] = vv.y;
        xs[(rowb + 2) * 68 + wp] = vv.z;
        xs[(rowb + 3) * 68 + wp] = vv.w;
    }
    __syncthreads();

    const int q = tid & 3;
    const int c = (tid >> 2) & 7;
    const int slot = tid >> 5;
    const float4* xs4 = (const float4*)xs;

    const _Float16 pinf16 = (_Float16)POS_INF;
    hv4 acc[8];
#pragma unroll
    for (int i = 0; i < 8; ++i)
        acc[i] = (hv4){pinf16, pinf16, pinf16, pinf16};

#pragma unroll
    for (int k2 = 0; k2 < 3; ++k2) {
        hv4 ke9[9];
#pragma unroll
        for (int t9 = 0; t9 < 9; ++t9) {
            int dy = t9 / 3, dx = t9 % 3;
            int a0 = 2 - dy, b0 = 2 - dx;
            int i, jj;
            ROT_G(g, a0, b0, i, jj);
            int ka, kb, kc;
            if (k2 == 0)      { ka = 2 - jj; kb = i;      kc = 2; }
            else if (k2 == 1) { ka = i;      kb = jj;     kc = 1; }
            else              { ka = jj;     kb = 2 - i;  kc = 0; }
            ke9[t9] = f4_to_hv4(ker4[((ka * 3 + kb) * 3 + kc) * 32 + c * 4 + q]);
        }
#pragma unroll
        for (int dy = 0; dy < 3; ++dy) {
            const int base4 = ((k2 * 3 + dy) * 8 + c) * 17 + slot * 2;
            float4 xa = xs4[base4];
            float4 xb = xs4[base4 + 1];
            float4 xc = xs4[base4 + 2];
            float xw[12] = {xa.x, xa.y, xa.z, xa.w,
                            xb.x, xb.y, xb.z, xb.w,
                            xc.x, xc.y, xc.z, xc.w};
            hv4 xv[12];
#pragma unroll
            for (int i = 0; i < 12; ++i)
                xv[i] = bcast16(xw[i]);
#pragma unroll
            for (int dx = 0; dx < 3; ++dx) {
                hv4 kv = ke9[dy * 3 + dx];
#pragma unroll
                for (int i = 0; i < 8; ++i)
                    acc[i] = __builtin_elementwise_min(acc[i], xv[i + dx] - kv);
            }
        }
    }

    const int row = (b * 4 + g) * HH + h;
    const size_t obase = ((size_t)row * 66 + slot * 8 + 1) * 32 + c * 4 + q;
#pragma unroll
    for (int i = 0; i < 8; ++i)
        ero[obase + (size_t)i * 32] = acc[i];

    const hv4 ninf = {(_Float16)NEG_INF, (_Float16)NEG_INF,
                      (_Float16)NEG_INF, (_Float16)NEG_INF};
    if (tid < 32)
        ero[(size_t)row * 66 * 32 + tid] = ninf;
    else if (tid < 64)
        ero[((size_t)row * 66 + 65) * 32 + (tid - 32)] = ninf;
}

// ======================= kernel 2: j-fused dilation (packed f16) ==================
// block = (b, hs:16, ws:8); thread = (slot,c,q); w = ws*8+slot.
// Outputs: all 4 j x 4 rows (hs*4 .. hs*4+3). Per gsrc plane, consumer pairs
// (j=(gsrc+1-k)%4, k) share each ero row load (6 rows/plane, 3 taps each).
__global__ __launch_bounds__(256) void dilate_j4(const hv4* __restrict__ ero,
                                                 const float* __restrict__ ker,
                                                 float* __restrict__ out) {
    const int tid = threadIdx.x;
    const int q = tid & 3;
    const int c = (tid >> 2) & 7;
    const int slot = tid >> 5;
    const int idx = blockIdx.x;
    const int ws = idx & 7;
    const int hs = (idx >> 3) & 15;
    const int b = idx >> 7;
    const int w = ws * 8 + slot;

    const float4* ker4 = (const float4*)ker;

    const hv4 ninf = {(_Float16)NEG_INF, (_Float16)NEG_INF,
                      (_Float16)NEG_INF, (_Float16)NEG_INF};
    hv4 acc[4][4];   // [j][local row]
#pragma unroll
    for (int jp = 0; jp < 4; ++jp)
#pragma unroll
        for (int rr = 0; rr < 4; ++rr)
            acc[jp][rr] = ninf;

#pragma unroll
    for (int gsrc = 0; gsrc < 4; ++gsrc) {
        // kernel taps for the 3 (j,k) pairs consuming this plane
        hv4 kd[3][9];
#pragma unroll
        for (int k = 0; k < 3; ++k) {
            const int jp = (gsrc + 1 - k + 4) & 3;
#pragma unroll
            for (int t9 = 0; t9 < 9; ++t9) {
                int dy = t9 / 3, dx = t9 % 3;
                int i, jj;
                ROT_G(jp, dy, dx, i, jj);
                kd[k][t9] = f4_to_hv4(ker4[((i * 3 + jj) * 3 + k) * 32 + c * 4 + q]);
            }
        }
        const size_t pb = ((size_t)(b * 4 + gsrc) * HH * 66 + w) * 32 + c * 4 + q;
#pragma unroll
        for (int ei = 0; ei < 6; ++ei) {
            const int er = hs * 4 - 1 + ei;
            if ((unsigned)er >= HH) continue;            // wave-uniform
            const size_t rb = pb + (size_t)er * 66 * 32;
            hv4 e0 = ero[rb];
            hv4 e1 = ero[rb + 32];
            hv4 e2 = ero[rb + 64];
#pragma unroll
            for (int k = 0; k < 3; ++k) {
                const int jp = (gsrc + 1 - k + 4) & 3;
#pragma unroll
                for (int dy = 0; dy < 3; ++dy) {
                    const int rr = ei - dy;              // local out row
                    if ((unsigned)rr >= 4) continue;
                    acc[jp][rr] = __builtin_elementwise_max(acc[jp][rr], e0 + kd[k][dy * 3 + 0]);
                    acc[jp][rr] = __builtin_elementwise_max(acc[jp][rr], e1 + kd[k][dy * 3 + 1]);
                    acc[jp][rr] = __builtin_elementwise_max(acc[jp][rr], e2 + kd[k][dy * 3 + 2]);
                }
            }
        }
    }

    // c-sum in f32 via xor-shuffle (c = lane bits 2..4), then store
    float4* out4 = (float4*)out;
#pragma unroll
    for (int jp = 0; jp < 4; ++jp)
#pragma unroll
        for (int rr = 0; rr < 4; ++rr) {
            hv4 a = acc[jp][rr];
            float4 s = make_float4((float)a.x, (float)a.y, (float)a.z, (float)a.w);
#pragma unroll
            for (int off = 4; off <= 16; off <<= 1) {
                s.x += __shfl_xor(s.x, off, 64);
                s.y += __shfl_xor(s.y, off, 64);
                s.z += __shfl_xor(s.z, off, 64);
                s.w += __shfl_xor(s.w, off, 64);
            }
            if (c == 0) {
                const int row = (b * 4 + jp) * HH + hs * 4 + rr;
                out4[((size_t)row * WW + w) * 4 + q] = s;
            }
        }
}

// ============== fallback: PASSED fused kernel (258 us, R5) ==============
__global__ __launch_bounds__(256, 3) void opening_fused_fb(
    const float* __restrict__ x, const float* __restrict__ ker, float* __restrict__ out)
{
    __shared__ __align__(16) float xs[8 * 4 * 144];
    __shared__ float4 es4[4 * 4 * 100];
    __shared__ float4 ke4[27 * 4 * 4];
    __shared__ float4 kd4[9 * 4 * 4];

    const int tid = threadIdx.x;
    const int tileX = blockIdx.x & 7;
    const int tileY = (blockIdx.x >> 3) & 7;
    const int j = (blockIdx.x >> 6) & 3;
    const int b = blockIdx.x >> 8;
    const float4* ker4 = (const float4*)ker;
    const float4* x4 = (const float4*)x;

    for (int t = tid; t < 1152; t += 256) {
        int q01 = t & 1;
        int cell = t >> 1;
        int g = cell / 144;
        int rem = cell - g * 144;
        int r = rem / 12;
        int s = rem - r * 12;
        int h = tileY * 8 - 2 + r;
        int w = tileX * 8 - 2 + s;
        float4 v;
        if ((unsigned)h < HH && (unsigned)w < WW)
            v = x4[(((b * 4 + g) * HH + h) * WW + w) * 2 + q01];
        else
            v = make_float4(POS_INF, POS_INF, POS_INF, POS_INF);
        int c0 = q01 * 4;
        xs[((c0 + 0) * 4 + g) * 144 + rem] = v.x;
        xs[((c0 + 1) * 4 + g) * 144 + rem] = v.y;
        xs[((c0 + 2) * 4 + g) * 144 + rem] = v.z;
        xs[((c0 + 3) * 4 + g) * 144 + rem] = v.w;
    }
    __syncthreads();

    const int q_o = tid & 3;
    const int ox = (tid >> 2) & 7;
    const int oy = tid >> 5;

    float4 acc[8];
#pragma unroll
    for (int c = 0; c < 8; ++c)
        acc[c] = make_float4(NEG_INF, NEG_INF, NEG_INF, NEG_INF);

    for (int k = 0; k < 3; ++k) {
        const int gsrc = (j + k + 3) & 3;
#pragma unroll
        for (int cg = 0; cg < 2; ++cg) {
            for (int t = tid; t < 576; t += 256) {
                if (t < 432) {
                    int q = t & 3;
                    int c4 = (t >> 2) & 3;
                    int tap = t >> 4;
                    int k2 = tap % 3;
                    int dxdy = tap / 3;
                    int dx = dxdy % 3;
                    int dy = dxdy / 3;
                    int a0 = 2 - dy, b0 = 2 - dx;
                    int i, jj;
                    ROT_G(gsrc, a0, b0, i, jj);
                    int ka, kb, kc;
                    if (k2 == 0)      { ka = 2 - jj; kb = i;      kc = 2; }
                    else if (k2 == 1) { ka = i;      kb = jj;     kc = 1; }
                    else              { ka = jj;     kb = 2 - i;  kc = 0; }
                    int c = cg * 4 + c4;
                    ke4[t] = ker4[((ka * 3 + kb) * 3 + kc) * 32 + c * 4 + q];
                } else {
                    int u = t - 432;
                    int q = u & 3;
                    int c4 = (u >> 2) & 3;
                    int dydx = u >> 4;
                    int dx = dydx % 3;
                    int dy = dydx / 3;
                    int i, jj;
                    ROT_G(j, dy, dx, i, jj);
                    int c = cg * 4 + c4;
                    kd4[u] = ker4[((i * 3 + jj) * 3 + k) * 32 + c * 4 + q];
                }
            }
            __syncthreads();

            for (int it = 0; it < 2; ++it) {
                int id = tid + (it << 8);
                int c4 = id >> 7;
                int p = id & 127;
                if (p >= 100) continue;
                int ey = (p * 205) >> 11;
                int ex = p - ey * 10;
                int h_es = tileY * 8 - 1 + ey;
                int w_es = tileX * 8 - 1 + ex;
                float4 b0, b1, b2, b3;
                if ((unsigned)h_es < HH && (unsigned)w_es < WW) {
                    b0 = b1 = b2 = b3 = make_float4(POS_INF, POS_INF, POS_INF, POS_INF);
                    int c = cg * 4 + c4;
#pragma unroll
                    for (int k2 = 0; k2 < 3; ++k2) {
                        int g2 = (gsrc + k2 + 3) & 3;
                        int base = (c * 4 + g2) * 144 + ey * 12 + ex;
#pragma unroll
                        for (int dy = 0; dy < 3; ++dy)
#pragma unroll
                            for (int dx = 0; dx < 3; ++dx) {
                                float v = xs[base + dy * 12 + dx];
                                const float4* kk = &ke4[(((dy * 3 + dx) * 3 + k2) * 4 + c4) * 4];
                                float4 kv;
                                kv = kk[0];
                                b0.x = fminf(b0.x, v - kv.x); b0.y = fminf(b0.y, v - kv.y);
                                b0.z = fminf(b0.z, v - kv.z); b0.w = fminf(b0.w, v - kv.w);
                                kv = kk[1];
                                b1.x = fminf(b1.x, v - kv.x); b1.y = fminf(b1.y, v - kv.y);
                                b1.z = fminf(b1.z, v - kv.z); b1.w = fminf(b1.w, v - kv.w);
                                kv = kk[2];
                                b2.x = fminf(b2.x, v - kv.x); b2.y = fminf(b2.y, v - kv.y);
                                b2.z = fminf(b2.z, v - kv.z); b2.w = fminf(b2.w, v - kv.w);
                                kv = kk[3];
                                b3.x = fminf(b3.x, v - kv.x); b3.y = fminf(b3.y, v - kv.y);
                                b3.z = fminf(b3.z, v - kv.z); b3.w = fminf(b3.w, v - kv.w);
                            }
                    }
                } else {
                    b0 = b1 = b2 = b3 = make_float4(NEG_INF, NEG_INF, NEG_INF, NEG_INF);
                }
                int eb = (c4 * 4) * 100 + p;
                es4[eb] = b0; es4[eb + 100] = b1; es4[eb + 200] = b2; es4[eb + 300] = b3;
            }
            __syncthreads();

#pragma unroll
            for (int c4 = 0; c4 < 4; ++c4) {
                float4 a = acc[cg * 4 + c4];
#pragma unroll
                for (int dy = 0; dy < 3; ++dy)
#pragma unroll
                    for (int dx = 0; dx < 3; ++dx) {
                        int pos = (oy + dy) * 10 + (ox + dx);
                        float4 e = es4[(c4 * 4 + q_o) * 100 + pos];
                        float4 kv = kd4[(dy * 3 + dx) * 16 + c4 * 4 + q_o];
                        a.x = fmaxf(a.x, e.x + kv.x);
                        a.y = fmaxf(a.y, e.y + kv.y);
                        a.z = fmaxf(a.z, e.z + kv.z);
                        a.w = fmaxf(a.w, e.w + kv.w);
                    }
                acc[cg * 4 + c4] = a;
            }
            __syncthreads();
        }
    }

    float4 s = acc[0];
#pragma unroll
    for (int c = 1; c < 8; ++c) {
        s.x += acc[c].x; s.y += acc[c].y; s.z += acc[c].z; s.w += acc[c].w;
    }
    const int h = tileY * 8 + oy;
    const int w = tileX * 8 + ox;
    ((float4*)out)[(((b * 4 + j) * HH + h) * WW + w) * 4 + q_o] = s;
}

extern "C" void kernel_launch(void* const* d_in, const int* in_sizes, int n_in,
                              void* d_out, int out_size, void* d_ws, size_t ws_size,
                              hipStream_t stream) {
    const float* x = (const float*)d_in[0];
    const float* ker = (const float*)d_in[1];
    float* out = (float*)d_out;

    const size_t ero_f16_bytes = (size_t)16 * HH * 66 * 32 * 8;   // 17,301,504

    if (ws_size >= ero_f16_bytes) {
        hv4* ero = (hv4*)d_ws;
        erode_t<<<1024, 256, 0, stream>>>(x, ker, ero);
        dilate_j4<<<512, 256, 0, stream>>>(ero, ker, out);   // (b:4, hs:16, ws:8)
    } else {
        opening_fused_fb<<<1024, 256, 0, stream>>>(x, ker, out);
    }
}

// Round 17
// 91.907 us; speedup vs baseline: 1.1554x; 1.1554x over previous
//
#include <hip/hip_runtime.h>

// OpeningP4: x [4,4,64,64,8] f32, kernel [3,3,3,8,16] f32 -> out [4,4,64,64,16] f32.
// v17 = exact revert to R14 (91.5us, session best). R15 (XCD swizzle) and R16
// (j-fused dilate) both failed to beat it; this restores the proven configuration.
//  - erode: block=(b,g,h), LDS x-tile (stride-68, b128 reads), packed-f16 min-chain,
//    f16 ero store (17.3MB, w-padded with -inf borders)
//  - dilate: block=(b,j,hs,ws), h-strip streaming (ero row loaded once -> 3 out rows),
//    packed f16 max/add, f32 xor-shuffle c-sum
// Harness poison-fill of d_ws (268MB, ~44us @ ~76% HBM peak) is a fixed timed cost.
// Rotation algebra verbatim from PASSED rounds (absmax 0.0625).

#define HH 64
#define WW 64
#define NEG_INF (-__builtin_inff())
#define POS_INF (__builtin_inff())

#define ROT_G(G, A, B, I, J) do { switch (G) { \
    case 0:  I = (A);     J = (B);     break; \
    case 1:  I = (B);     J = 2 - (A); break; \
    case 2:  I = 2 - (A); J = 2 - (B); break; \
    default: I = 2 - (B); J = (A);     break; } } while (0)

typedef _Float16 hv4 __attribute__((ext_vector_type(4)));   // 8 B, v_pk_* pairs

__device__ __forceinline__ hv4 f4_to_hv4(float4 v) {
    hv4 r;
    r.x = (_Float16)v.x; r.y = (_Float16)v.y;
    r.z = (_Float16)v.z; r.w = (_Float16)v.w;
    return r;
}

__device__ __forceinline__ hv4 bcast16(float v) {
    _Float16 p = (_Float16)v;
    return (hv4){p, p, p, p};
}

// ======================= kernel 1: erosion (packed f16 math) ======================
// block = (b,g,h); thread = (slot,c,q); pixels w = slot*8 + i, i=0..7 (consecutive).
// ero layout (hv4 elems): ((bg*64+h)*66 + wp)*32 + c*4 + q, wp = w+1, -inf borders.
__global__ __launch_bounds__(256) void erode_t(const float* __restrict__ x,
                                               const float* __restrict__ ker,
                                               hv4* __restrict__ ero) {
    // [p*3+r][c][wp0..67]: stride 68 -> 16B-aligned b128 at every c, banks <=2-way
    __shared__ __align__(16) float xs[9 * 8 * 68];   // 19584 B

    const int tid = threadIdx.x;
    const int h = blockIdx.x & 63;
    const int g = (blockIdx.x >> 6) & 3;
    const int b = blockIdx.x >> 8;

    const float4* x4 = (const float4*)x;
    const float4* ker4 = (const float4*)ker;

    // stage 3 planes x[(g+p-1)&3], rows h-1..h+1, cols -1..64 (wp 0..65), OOB=+inf
    for (int t = tid; t < 1188; t += 256) {
        int q01 = t & 1;
        int u = t >> 1;
        int wp = u % 66;
        int v = u / 66;
        int r = v % 3;
        int p = v / 3;
        int g2 = (g + p + 3) & 3;
        int h2 = h - 1 + r;
        int w2 = wp - 1;
        float4 vv;
        if ((unsigned)h2 < HH && (unsigned)w2 < WW)
            vv = x4[(((b * 4 + g2) * HH + h2) * WW + w2) * 2 + q01];
        else
            vv = make_float4(POS_INF, POS_INF, POS_INF, POS_INF);
        int rowb = (p * 3 + r) * 8 + q01 * 4;
        xs[(rowb + 0) * 68 + wp] = vv.x;
        xs[(rowb + 1) * 68 + wp] = vv.y;
        xs[(rowb + 2) * 68 + wp] = vv.z;
        xs[(rowb + 3) * 68 + wp] = vv.w;
    }
    __syncthreads();

    const int q = tid & 3;
    const int c = (tid >> 2) & 7;
    const int slot = tid >> 5;
    const float4* xs4 = (const float4*)xs;

    const _Float16 pinf16 = (_Float16)POS_INF;
    hv4 acc[8];
#pragma unroll
    for (int i = 0; i < 8; ++i)
        acc[i] = (hv4){pinf16, pinf16, pinf16, pinf16};

#pragma unroll
    for (int k2 = 0; k2 < 3; ++k2) {
        // KE_g[dy,dx,k2,c,f4=q]: 9 coalesced global reads (L1-hot), converted to f16
        hv4 ke9[9];
#pragma unroll
        for (int t9 = 0; t9 < 9; ++t9) {
            int dy = t9 / 3, dx = t9 % 3;
            int a0 = 2 - dy, b0 = 2 - dx;
            int i, jj;
            ROT_G(g, a0, b0, i, jj);
            int ka, kb, kc;
            if (k2 == 0)      { ka = 2 - jj; kb = i;      kc = 2; }
            else if (k2 == 1) { ka = i;      kb = jj;     kc = 1; }
            else              { ka = jj;     kb = 2 - i;  kc = 0; }
            ke9[t9] = f4_to_hv4(ker4[((ka * 3 + kb) * 3 + kc) * 32 + c * 4 + q]);
        }
#pragma unroll
        for (int dy = 0; dy < 3; ++dy) {
            // 12-float window (wp = slot*8 .. slot*8+11) as 3x ds_read_b128
            const int base4 = ((k2 * 3 + dy) * 8 + c) * 17 + slot * 2;
            float4 xa = xs4[base4];
            float4 xb = xs4[base4 + 1];
            float4 xc = xs4[base4 + 2];
            float xw[12] = {xa.x, xa.y, xa.z, xa.w,
                            xb.x, xb.y, xb.z, xb.w,
                            xc.x, xc.y, xc.z, xc.w};
            hv4 xv[12];
#pragma unroll
            for (int i = 0; i < 12; ++i)
                xv[i] = bcast16(xw[i]);
#pragma unroll
            for (int dx = 0; dx < 3; ++dx) {
                hv4 kv = ke9[dy * 3 + dx];
#pragma unroll
                for (int i = 0; i < 8; ++i)
                    acc[i] = __builtin_elementwise_min(acc[i], xv[i + dx] - kv);
            }
        }
    }

    // store: wp = slot*8 + i + 1; lanes (q,c) -> 256B contiguous per (slot,i)
    const int row = (b * 4 + g) * HH + h;
    const size_t obase = ((size_t)row * 66 + slot * 8 + 1) * 32 + c * 4 + q;
#pragma unroll
    for (int i = 0; i < 8; ++i)
        ero[obase + (size_t)i * 32] = acc[i];

    // -inf border columns wp=0, wp=65 (32 hv4 each)
    const hv4 ninf = {(_Float16)NEG_INF, (_Float16)NEG_INF,
                      (_Float16)NEG_INF, (_Float16)NEG_INF};
    if (tid < 32)
        ero[(size_t)row * 66 * 32 + tid] = ninf;
    else if (tid < 64)
        ero[((size_t)row * 66 + 65) * 32 + (tid - 32)] = ninf;
}

// ======================= kernel 2: dilation (packed f16) ==========================
// block = (b,j,hs,ws); thread = (slot,c,q); w = ws*8+slot, out rows hs*8..hs*8+7.
// Each ero row (10 per strip) loaded once (3 taps) feeds 3 out rows.
__global__ __launch_bounds__(256) void dilate_t(const hv4* __restrict__ ero,
                                                const float* __restrict__ ker,
                                                float* __restrict__ out) {
    const int tid = threadIdx.x;
    const int q = tid & 3;
    const int c = (tid >> 2) & 7;
    const int slot = tid >> 5;
    const int ws = blockIdx.x & 7;
    const int hs = (blockIdx.x >> 3) & 7;
    const int j = (blockIdx.x >> 6) & 3;
    const int b = blockIdx.x >> 8;
    const int w = ws * 8 + slot;

    const float4* ker4 = (const float4*)ker;

    const hv4 ninf = {(_Float16)NEG_INF, (_Float16)NEG_INF,
                      (_Float16)NEG_INF, (_Float16)NEG_INF};
    hv4 acc[8];
#pragma unroll
    for (int r = 0; r < 8; ++r)
        acc[r] = ninf;

#pragma unroll
    for (int k = 0; k < 3; ++k) {
        const int gsrc = (j + k + 3) & 3;
        hv4 kd9[9];
#pragma unroll
        for (int t9 = 0; t9 < 9; ++t9) {
            int dy = t9 / 3, dx = t9 % 3;
            int i, jj;
            ROT_G(j, dy, dx, i, jj);
            kd9[t9] = f4_to_hv4(ker4[((i * 3 + jj) * 3 + k) * 32 + c * 4 + q]);
        }
        // taps at wp = w, w+1, w+2 -> hv4 offsets +0, +32, +64
        const size_t pb = ((size_t)(b * 4 + gsrc) * HH * 66 + w) * 32 + c * 4 + q;
#pragma unroll
        for (int ei = 0; ei < 10; ++ei) {
            const int er = hs * 8 - 1 + ei;
            if ((unsigned)er >= HH) continue;           // wave-uniform
            const size_t rb = pb + (size_t)er * 66 * 32;
            hv4 e0 = ero[rb];
            hv4 e1 = ero[rb + 32];
            hv4 e2 = ero[rb + 64];
#pragma unroll
            for (int dy = 0; dy < 3; ++dy) {
                const int rr = ei - dy;                  // out local row
                if ((unsigned)rr >= 8) continue;
                acc[rr] = __builtin_elementwise_max(acc[rr], e0 + kd9[dy * 3 + 0]);
                acc[rr] = __builtin_elementwise_max(acc[rr], e1 + kd9[dy * 3 + 1]);
                acc[rr] = __builtin_elementwise_max(acc[rr], e2 + kd9[dy * 3 + 2]);
            }
        }
    }

    // c-sum in f32 via xor-shuffle (c = lane bits 2..4), then store
    float4* out4 = (float4*)out;
    const int bjbase = (b * 4 + j) * HH + hs * 8;
#pragma unroll
    for (int r = 0; r < 8; ++r) {
        float4 s = make_float4((float)acc[r].x, (float)acc[r].y,
                               (float)acc[r].z, (float)acc[r].w);
#pragma unroll
        for (int off = 4; off <= 16; off <<= 1) {
            s.x += __shfl_xor(s.x, off, 64);
            s.y += __shfl_xor(s.y, off, 64);
            s.z += __shfl_xor(s.z, off, 64);
            s.w += __shfl_xor(s.w, off, 64);
        }
        if (c == 0)
            out4[((size_t)(bjbase + r) * WW + w) * 4 + q] = s;
    }
}

// ============== fallback: PASSED fused kernel (258 us, R5) ==============
__global__ __launch_bounds__(256, 3) void opening_fused_fb(
    const float* __restrict__ x, const float* __restrict__ ker, float* __restrict__ out)
{
    __shared__ __align__(16) float xs[8 * 4 * 144];
    __shared__ float4 es4[4 * 4 * 100];
    __shared__ float4 ke4[27 * 4 * 4];
    __shared__ float4 kd4[9 * 4 * 4];

    const int tid = threadIdx.x;
    const int tileX = blockIdx.x & 7;
    const int tileY = (blockIdx.x >> 3) & 7;
    const int j = (blockIdx.x >> 6) & 3;
    const int b = blockIdx.x >> 8;
    const float4* ker4 = (const float4*)ker;
    const float4* x4 = (const float4*)x;

    for (int t = tid; t < 1152; t += 256) {
        int q01 = t & 1;
        int cell = t >> 1;
        int g = cell / 144;
        int rem = cell - g * 144;
        int r = rem / 12;
        int s = rem - r * 12;
        int h = tileY * 8 - 2 + r;
        int w = tileX * 8 - 2 + s;
        float4 v;
        if ((unsigned)h < HH && (unsigned)w < WW)
            v = x4[(((b * 4 + g) * HH + h) * WW + w) * 2 + q01];
        else
            v = make_float4(POS_INF, POS_INF, POS_INF, POS_INF);
        int c0 = q01 * 4;
        xs[((c0 + 0) * 4 + g) * 144 + rem] = v.x;
        xs[((c0 + 1) * 4 + g) * 144 + rem] = v.y;
        xs[((c0 + 2) * 4 + g) * 144 + rem] = v.z;
        xs[((c0 + 3) * 4 + g) * 144 + rem] = v.w;
    }
    __syncthreads();

    const int q_o = tid & 3;
    const int ox = (tid >> 2) & 7;
    const int oy = tid >> 5;

    float4 acc[8];
#pragma unroll
    for (int c = 0; c < 8; ++c)
        acc[c] = make_float4(NEG_INF, NEG_INF, NEG_INF, NEG_INF);

    for (int k = 0; k < 3; ++k) {
        const int gsrc = (j + k + 3) & 3;
#pragma unroll
        for (int cg = 0; cg < 2; ++cg) {
            for (int t = tid; t < 576; t += 256) {
                if (t < 432) {
                    int q = t & 3;
                    int c4 = (t >> 2) & 3;
                    int tap = t >> 4;
                    int k2 = tap % 3;
                    int dxdy = tap / 3;
                    int dx = dxdy % 3;
                    int dy = dxdy / 3;
                    int a0 = 2 - dy, b0 = 2 - dx;
                    int i, jj;
                    ROT_G(gsrc, a0, b0, i, jj);
                    int ka, kb, kc;
                    if (k2 == 0)      { ka = 2 - jj; kb = i;      kc = 2; }
                    else if (k2 == 1) { ka = i;      kb = jj;     kc = 1; }
                    else              { ka = jj;     kb = 2 - i;  kc = 0; }
                    int c = cg * 4 + c4;
                    ke4[t] = ker4[((ka * 3 + kb) * 3 + kc) * 32 + c * 4 + q];
                } else {
                    int u = t - 432;
                    int q = u & 3;
                    int c4 = (u >> 2) & 3;
                    int dydx = u >> 4;
                    int dx = dydx % 3;
                    int dy = dydx / 3;
                    int i, jj;
                    ROT_G(j, dy, dx, i, jj);
                    int c = cg * 4 + c4;
                    kd4[u] = ker4[((i * 3 + jj) * 3 + k) * 32 + c * 4 + q];
                }
            }
            __syncthreads();

            for (int it = 0; it < 2; ++it) {
                int id = tid + (it << 8);
                int c4 = id >> 7;
                int p = id & 127;
                if (p >= 100) continue;
                int ey = (p * 205) >> 11;
                int ex = p - ey * 10;
                int h_es = tileY * 8 - 1 + ey;
                int w_es = tileX * 8 - 1 + ex;
                float4 b0, b1, b2, b3;
                if ((unsigned)h_es < HH && (unsigned)w_es < WW) {
                    b0 = b1 = b2 = b3 = make_float4(POS_INF, POS_INF, POS_INF, POS_INF);
                    int c = cg * 4 + c4;
#pragma unroll
                    for (int k2 = 0; k2 < 3; ++k2) {
                        int g2 = (gsrc + k2 + 3) & 3;
                        int base = (c * 4 + g2) * 144 + ey * 12 + ex;
#pragma unroll
                        for (int dy = 0; dy < 3; ++dy)
#pragma unroll
                            for (int dx = 0; dx < 3; ++dx) {
                                float v = xs[base + dy * 12 + dx];
                                const float4* kk = &ke4[(((dy * 3 + dx) * 3 + k2) * 4 + c4) * 4];
                                float4 kv;
                                kv = kk[0];
                                b0.x = fminf(b0.x, v - kv.x); b0.y = fminf(b0.y, v - kv.y);
                                b0.z = fminf(b0.z, v - kv.z); b0.w = fminf(b0.w, v - kv.w);
                                kv = kk[1];
                                b1.x = fminf(b1.x, v - kv.x); b1.y = fminf(b1.y, v - kv.y);
                                b1.z = fminf(b1.z, v - kv.z); b1.w = fminf(b1.w, v - kv.w);
                                kv = kk[2];
                                b2.x = fminf(b2.x, v - kv.x); b2.y = fminf(b2.y, v - kv.y);
                                b2.z = fminf(b2.z, v - kv.z); b2.w = fminf(b2.w, v - kv.w);
                                kv = kk[3];
                                b3.x = fminf(b3.x, v - kv.x); b3.y = fminf(b3.y, v - kv.y);
                                b3.z = fminf(b3.z, v - kv.z); b3.w = fminf(b3.w, v - kv.w);
                            }
                    }
                } else {
                    b0 = b1 = b2 = b3 = make_float4(NEG_INF, NEG_INF, NEG_INF, NEG_INF);
                }
                int eb = (c4 * 4) * 100 + p;
                es4[eb] = b0; es4[eb + 100] = b1; es4[eb + 200] = b2; es4[eb + 300] = b3;
            }
            __syncthreads();

#pragma unroll
            for (int c4 = 0; c4 < 4; ++c4) {
                float4 a = acc[cg * 4 + c4];
#pragma unroll
                for (int dy = 0; dy < 3; ++dy)
#pragma unroll
                    for (int dx = 0; dx < 3; ++dx) {
                        int pos = (oy + dy) * 10 + (ox + dx);
                        float4 e = es4[(c4 * 4 + q_o) * 100 + pos];
                        float4 kv = kd4[(dy * 3 + dx) * 16 + c4 * 4 + q_o];
                        a.x = fmaxf(a.x, e.x + kv.x);
                        a.y = fmaxf(a.y, e.y + kv.y);
                        a.z = fmaxf(a.z, e.z + kv.z);
                        a.w = fmaxf(a.w, e.w + kv.w);
                    }
                acc[cg * 4 + c4] = a;
            }
            __syncthreads();
        }
    }

    float4 s = acc[0];
#pragma unroll
    for (int c = 1; c < 8; ++c) {
        s.x += acc[c].x; s.y += acc[c].y; s.z += acc[c].z; s.w += acc[c].w;
    }
    const int h = tileY * 8 + oy;
    const int w = tileX * 8 + ox;
    ((float4*)out)[(((b * 4 + j) * HH + h) * WW + w) * 4 + q_o] = s;
}

extern "C" void kernel_launch(void* const* d_in, const int* in_sizes, int n_in,
                              void* d_out, int out_size, void* d_ws, size_t ws_size,
                              hipStream_t stream) {
    const float* x = (const float*)d_in[0];
    const float* ker = (const float*)d_in[1];
    float* out = (float*)d_out;

    const size_t ero_f16_bytes = (size_t)16 * HH * 66 * 32 * 8;   // 17,301,504

    if (ws_size >= ero_f16_bytes) {
        hv4* ero = (hv4*)d_ws;
        erode_t<<<1024, 256, 0, stream>>>(x, ker, ero);
        dilate_t<<<1024, 256, 0, stream>>>(ero, ker, out);
    } else {
        opening_fused_fb<<<1024, 256, 0, stream>>>(x, ker, out);
    }
}